// Round 1
// baseline (250.168 us; speedup 1.0000x reference)
//
#include <hip/hip_runtime.h>

#define Bb 8
#define Cc 64
#define Hh 200
#define Ww 320
#define Nn 48
#define WDd 80

// ---------------------------------------------------------------------------
// Kernel 1: per (b,n) — gather row idx, mean over WD, vk = Wk·kf_mean + bk,
// then fold through Wf/bf:  WeffT[b][c'][n] = sum_c vk[c]*Wf[c][c']
//                           beff[b][n]     = sum_c vk[c]*bf[c] + vk[64]
// Also writes centers output. 384 blocks of 64 threads — negligible cost.
// ---------------------------------------------------------------------------
__global__ __launch_bounds__(64) void prep_kernel(
    const float* __restrict__ kf, const float* __restrict__ Wk,
    const float* __restrict__ bk, const float* __restrict__ Wf,
    const float* __restrict__ bf, const float* __restrict__ db,
    const int* __restrict__ pad_w,
    float* __restrict__ weffT, float* __restrict__ beff,
    float* __restrict__ centers)
{
    const int n = blockIdx.x, b = blockIdx.y, tid = threadIdx.x;
    const float stride = (float)pad_w[0] / (float)Ww;   // = 4.0
    const float yc = (db[(b*Nn + n)*4 + 1] + db[(b*Nn + n)*4 + 3]) / (2.0f * stride);
    const int idx = (int)yc;   // trunc, matches astype(int32); always in [0,H)

    __shared__ float kfm[Cc];
    __shared__ float vk[Cc + 1];

    // mean over WD of kernel_feats[b, tid, idx, :]
    const float* row = kf + ((size_t)(b*Cc + tid)*Hh + idx)*WDd;
    float s = 0.f;
    #pragma unroll
    for (int w0 = 0; w0 < WDd; ++w0) s += row[w0];
    kfm[tid] = s * (1.0f / (float)WDd);
    __syncthreads();

    // vk[o] = bk[o] + Wk[o,:]·kfm   (o = tid, plus o = 64 done by tid 0)
    {
        float a = bk[tid];
        #pragma unroll 8
        for (int c = 0; c < Cc; ++c) a = fmaf(Wk[tid*Cc + c], kfm[c], a);
        vk[tid] = a;
        if (tid == 0) {
            float a2 = bk[Cc];
            for (int c = 0; c < Cc; ++c) a2 = fmaf(Wk[Cc*Cc + c], kfm[c], a2);
            vk[Cc] = a2;
        }
    }
    __syncthreads();

    // WeffT[b][c'][n] = sum_c vk[c] * Wf[c][c']   (c' = tid)
    float wsum = 0.f;
    #pragma unroll 8
    for (int c = 0; c < Cc; ++c) wsum = fmaf(vk[c], Wf[c*Cc + tid], wsum);
    weffT[((size_t)b*Cc + tid)*Nn + n] = wsum;

    if (tid == 0) {
        float bb2 = vk[Cc];
        for (int c = 0; c < Cc; ++c) bb2 = fmaf(vk[c], bf[c], bb2);
        beff[b*Nn + n] = bb2;
        centers[b*Nn + n] = yc * stride;
    }
}

// ---------------------------------------------------------------------------
// Kernel 2: logits[b,n,h,w] = sum_c WeffT[b][c][n]*feats[b,c,h,w] + beff[b,n]
// masked with -1e8. One wave per 64 consecutive w. acc[48] in VGPRs.
// Weight reads are wave-uniform (b, c uniform) -> s_load + v_fmac sgpr-src.
// __ballot makes the skip branch wave-uniform: fully masked waves do no
// feats reads and no FMAs (≈65% of pixels are masked).
// ---------------------------------------------------------------------------
__global__ __launch_bounds__(64) void logits_kernel(
    const float* __restrict__ feats, const int* __restrict__ ishape,
    const int* __restrict__ pad_w, const float* __restrict__ weffT,
    const float* __restrict__ beff, float* __restrict__ out)
{
    const int b = blockIdx.z;
    const int h = blockIdx.y;
    const int w = blockIdx.x * 64 + threadIdx.x;

    const float stride = (float)pad_w[0] / (float)Ww;
    const int hlim = (int)((float)ishape[b*2 + 1] / stride);
    const int wlim = (int)((float)ishape[b*2 + 0] / stride);
    const bool act = (h < hlim) && (w < wlim);

    float acc[Nn];
    if (__ballot(act) != 0ULL) {            // wave-uniform branch
        const float* __restrict__ bv = beff + b*Nn;
        #pragma unroll
        for (int n = 0; n < Nn; ++n) acc[n] = bv[n];

        const float* __restrict__ fp = feats + ((size_t)(b*Cc)*Hh + h)*Ww + w;
        const float* __restrict__ wT = weffT + (size_t)b*Cc*Nn;
        #pragma unroll 4
        for (int c = 0; c < Cc; ++c) {
            const float fv = fp[(size_t)c * (Hh*Ww)];
            const float* __restrict__ wrow = wT + c*Nn;
            #pragma unroll
            for (int n = 0; n < Nn; ++n) acc[n] = fmaf(wrow[n], fv, acc[n]);
        }
    } else {
        #pragma unroll
        for (int n = 0; n < Nn; ++n) acc[n] = -1e8f;
    }

    float* op = out + ((size_t)(b*Nn)*Hh + h)*Ww + w;
    #pragma unroll
    for (int n = 0; n < Nn; ++n)
        op[(size_t)n * (Hh*Ww)] = act ? acc[n] : -1e8f;
}

extern "C" void kernel_launch(void* const* d_in, const int* in_sizes, int n_in,
                              void* d_out, int out_size, void* d_ws, size_t ws_size,
                              hipStream_t stream) {
    const float* feats  = (const float*)d_in[0];
    const float* kf     = (const float*)d_in[1];
    const float* Wk     = (const float*)d_in[2];
    const float* bk     = (const float*)d_in[3];
    const float* Wf     = (const float*)d_in[4];
    const float* bf     = (const float*)d_in[5];
    const float* db     = (const float*)d_in[6];
    const int*   ishape = (const int*)d_in[7];
    const int*   pad_w  = (const int*)d_in[8];

    float* out    = (float*)d_out;
    float* weffT  = (float*)d_ws;                      // B*64*48 floats
    float* beff   = weffT + (size_t)Bb*Cc*Nn;          // B*48 floats
    float* centers = out + (size_t)Bb*Nn*Hh*Ww;        // second output

    prep_kernel<<<dim3(Nn, Bb), 64, 0, stream>>>(
        kf, Wk, bk, Wf, bf, db, pad_w, weffT, beff, centers);

    logits_kernel<<<dim3(Ww/64, Hh, Bb), 64, 0, stream>>>(
        feats, ishape, pad_w, weffT, beff, out);
}